// Round 12
// baseline (982661.035 us; speedup 1.0000x reference)
//
#include <hip/hip_runtime.h>
#include <hip/hip_fp16.h>

typedef _Float16 f16;
typedef unsigned int u32;
typedef unsigned long long u64;
typedef _Float16 f16x4 __attribute__((ext_vector_type(4)));
typedef _Float16 f16x8 __attribute__((ext_vector_type(8)));
typedef float f32x4 __attribute__((ext_vector_type(4)));
typedef float f32x16 __attribute__((ext_vector_type(16)));

#define SEQ   512
#define HID   512
#define NSK   1024
#define INDIM 2048
#define HSTEP 32768          // f16 per timestep, layout [ug=u>>3][b][u&7]
#define NRING 32             // h1 local ring slots (2 MB: L2-resident, L1-stale-proof)

// ---- workspace layout (bytes) ----
#define H1PUB_OFF 0ull           // 32 MB  h1 published to MALL for L1 group
#define H2_OFF    33554432ull    // 32 MB  h2 (L1-local stores; proj reads after flush)
#define RING_OFF  67108864ull    // 2 MB   h1 local ring (XCD0 L2)
#define FCW_OFF   69206016ull    // 1 MB   fcW f16
#define BF_OFF    70254592ull    // 16 KB  folded biases [lyr][slot][gate][16]
#define SIDX_OFF  70270976ull    // 128 KB [t][b] gather index
#define L0F_OFF   70402048ull    // 2 KB   32 lines x 4 wave slots (XCD0-local)
#define L1F_OFF   70404096ull    // 2 KB   (XCD1-local)
#define PUBF_OFF  70406144ull    // 2 KB   32 per-slice publish epochs (MALL)
#define CNT_OFF   70408192ull    // 512 B  per-XCD role counters
#define W0P_OFF   70408704ull    // 8 MB   [col][slot][gate][16] f16

__device__ __forceinline__ float sigmoidf_(float x) {
    return 1.0f / (1.0f + __expf(-x));
}
__device__ __forceinline__ float tanhf_(float x) {
    return 2.0f * sigmoidf_(2.0f * x) - 1.0f;
}

// ---- XCD-local (L2-executed) sync ops: no sc1 -> atomic executes at local L2 ----
__device__ __forceinline__ void l2_swap32(u32* p, u32 v) {
    asm volatile("global_atomic_swap %0, %1, off" :: "v"(p), "v"(v) : "memory");
}
// sc0 load: bypass L1, read local L2 (where peer swaps landed). waitcnt inside.
__device__ __forceinline__ uint4 l2_load4(const u32* p) {
    uint4 r;
    asm volatile("global_load_dwordx4 %0, %1, off sc0\n\ts_waitcnt vmcnt(0)"
                 : "=&v"(r) : "v"(p) : "memory");
    return r;
}

// local-min spin over 32 packed flag lines; optional MALL pub-flag legs (lanes 32-63)
__device__ __forceinline__ void spin2(const u32* lf, u32 wantL,
                                      const u32* pf, u32 wantP, int lane) {
    int guard = 0;
    while (true) {
        bool bad = false;
        if (lane < 32) {
            uint4 v = l2_load4(lf + lane * 16);
            u32 mn = min(min(v.x, v.y), min(v.z, v.w));
            bad = mn < wantL;
        } else if (pf != nullptr) {
            u32 pv = __hip_atomic_load(pf + (lane - 32) * 16,
                                       __ATOMIC_RELAXED, __HIP_MEMORY_SCOPE_AGENT);
            bad = pv < wantP;
        }
        if (__ballot(bad) == 0ull) break;
        __builtin_amdgcn_s_sleep(1);
        if (++guard > (1 << 13)) break;   // bounded: broken sync -> visible absmax fail
    }
}

// ---- prep: fcW f16, folded bias, gather index, zero flags+counters ----
__global__ __launch_bounds__(256) void prep_kernel(
    const int* __restrict__ skills, const int* __restrict__ corrects,
    const float* __restrict__ fcW,
    const float* __restrict__ bih0, const float* __restrict__ bhh0,
    const float* __restrict__ bih1, const float* __restrict__ bhh1,
    f16* __restrict__ fcwh, float* __restrict__ bfold,
    int* __restrict__ sidx, u32* __restrict__ flagz)
{
    int i = blockIdx.x * 256 + threadIdx.x;
    if (i < NSK * HID) fcwh[i] = (f16)fcW[i];
    if (i < 4096) {   // bfold[lyr][slot][gate][16]
        int l = i >> 11, u = i & 15, g = (i >> 4) & 3, s = (i >> 6) & 31;
        int row = g * 512 + s * 16 + u;
        bfold[i] = l ? (bih1[row] + bhh1[row]) : (bih0[row] + bhh0[row]);
    }
    if (i < SEQ * 64) {
        int t = i >> 6, b = i & 63;
        int sk = skills[b * SEQ + t], co = corrects[b * SEQ + t];
        sidx[i] = (sk >= 0) ? (sk + NSK * ((co == 1) ? 0 : 1)) : -1;
    }
    if (i < 1664) flagz[i] = 0;   // l0f + l1f + pubf + cnt (6656 B contiguous)
}

// ---- W0P build: W0P[c][slot][gate][u16] = Wih0[gate*512 + slot*16 + u][c] ----
__global__ __launch_bounds__(256) void w0p_kernel(
    const float* __restrict__ Wih0, f16* __restrict__ w0p)
{
    __shared__ float tl[64][65];
    const int tid = threadIdx.x;
    const int ct = blockIdx.x & 31, rt = blockIdx.x >> 5;
    const int r0 = rt * 64, c0 = ct * 64;
#pragma unroll 4
    for (int i = 0; i < 16; ++i) {
        int rr = i * 4 + (tid >> 6);
        int cc = tid & 63;
        tl[rr][cc] = Wih0[(size_t)(r0 + rr) * INDIM + c0 + cc];
    }
    __syncthreads();
    const int g = r0 >> 9;
    const int s0 = (r0 & 511) >> 4;   // 4 slots per tile
    for (int task = tid; task < 512; task += 256) {
        int c = task >> 3, srel = (task >> 1) & 3, half = task & 1;
        f16 tmp[8];
#pragma unroll
        for (int j = 0; j < 8; ++j) tmp[j] = (f16)tl[srel * 16 + half * 8 + j][c];
        *(f16x8*)&w0p[(size_t)(c0 + c) * 2048 + (s0 + srel) * 64 + g * 16 + half * 8]
            = *(f16x8*)tmp;
    }
}

struct PArgs {
    const int* sidx; const f16* W0P;
    const float* Whh0; const float* Wih1; const float* Whh1;
    const float* bfold;
    f16* h1pub; f16* h2; f16* ring;
    u32* l0f; u32* l1f; u32* pubf; u32* cnt;
};

// ---- persistent 2-layer LSTM, XCD-partitioned (R12) ----
// 256 WGs (1/CU by 128KB LDS -> exactly 32/XCD). Each WG reads HW_REG_XCC_ID
// (hwreg 20, m09-verified) and self-claims a slot in its XCD's counter.
// XCD0 slots 0-31 = L0 group (owns units [slot*16,+16) of layer0);
// XCD1 slots 0-31 = L1 group; others exit. L0's h1 chain + flags live in
// XCD0's L2 (plain ring stores, sc0-only atomics/loads); L1's h2 chain in
// XCD1's L2. L0 additionally publishes h1 to MALL (agent exchange) with
// per-slice epoch flags certified AFTER per-wave vmcnt drain + s_barrier.
// Groups are decoupled: L0 sprints ahead; L1 polls pub epochs (normally
// already satisfied). Waves per WG: (ri = unit-octet, ci = batch-half);
// D = W(A,LDS) x h^T(B): in-register cell, proven R9-R11 mapping.
__global__ __launch_bounds__(256, 1) void lstm_mfma(PArgs a) {
    __shared__ f16 wlds[2 * 2 * 32 * 64 * 8];   // 128 KB [m][ri][f][lane][8]
    __shared__ u32 rsh[1];

    const int tid  = threadIdx.x;
    const int lane = tid & 63;
    const int w    = tid >> 6;

    u32 xcd;
    asm volatile("s_getreg_b32 %0, hwreg(20, 0, 8)" : "=s"(xcd));
    xcd &= 7;
    if (tid == 0) {
        u32 s = __hip_atomic_fetch_add(&a.cnt[xcd], 1u,
                                       __ATOMIC_RELAXED, __HIP_MEMORY_SCOPE_AGENT);
        rsh[0] = s;
    }
    __syncthreads();
    const int slot = (int)rsh[0];
    const bool isL1 = (xcd == 1);
    if (xcd >= 2 || slot >= 32) return;   // spectators exit whole-WG

    const int ri = w & 1;                 // unit octet within WG
    const int ci = w >> 1;                // batch half
    const int n  = lane & 31;
    const int nh = lane >> 5;
    const int b  = ci * 32 + n;           // batch (B col / cell lane)

    // ---- stage weights f32 -> f16 fragment-ordered LDS ----
    // L0: m0 = Whh0 (64 KB). L1: m0 = Wih1, m1 = Whh1 (128 KB).
    const int tot = isL1 ? 8192 : 4096;
    for (int i = tid; i < tot; i += 256) {
        int m = i >> 12, rem = i & 4095;
        int rr = rem >> 11, rem2 = rem & 2047;
        int f = rem2 >> 6, l = rem2 & 63;
        int ln = l & 31, lh = l >> 5;
        int row = (ln >> 3) * 512 + slot * 16 + rr * 8 + (ln & 7);
        int col = f * 16 + lh * 8;
        const float* src = isL1 ? (m ? a.Whh1 : a.Wih1) : a.Whh0;
        const float* sp = src + (size_t)row * HID + col;
        f16 tmp[8];
#pragma unroll
        for (int j = 0; j < 8; ++j) tmp[j] = (f16)sp[j];
        *(f16x8*)&wlds[(size_t)(((m * 2 + rr) * 32 + f) * 64 + l) * 8] = *(f16x8*)tmp;
    }

    // bias for cell lanes: units slot*16 + ri*8 + nh*4 + (0..3), 4 gates
    float4 bf0, bf1, bf2, bf3;
    {
        const int lyr = isL1 ? 1 : 0;
        const float* bp = a.bfold + ((lyr * 32 + slot) * 4) * 16 + ri * 8 + nh * 4;
        bf0 = *(const float4*)(bp + 0);
        bf1 = *(const float4*)(bp + 16);
        bf2 = *(const float4*)(bp + 32);
        bf3 = *(const float4*)(bp + 48);
    }

    float cst[4] = {0.0f, 0.0f, 0.0f, 0.0f};
    const size_t hidx = ((size_t)(slot * 2 + ri) * 64 + b) * 8 + nh * 4;

    // L0 x-gather prefetch for t=0
    uint2 xq0 = {0, 0}, xq1 = {0, 0}, xq2 = {0, 0}, xq3 = {0, 0};
    if (!isL1) {
        int sd = a.sidx[b];
        if (sd >= 0) {
            const f16* xp = a.W0P + (size_t)sd * 2048 + slot * 64 + ri * 8 + nh * 4;
            xq0 = *(const uint2*)(xp);
            xq1 = *(const uint2*)(xp + 16);
            xq2 = *(const uint2*)(xp + 32);
            xq3 = *(const uint2*)(xp + 48);
        }
    }

    __syncthreads();   // staging done

    if (!isL1) {
        // =================== L0 group (XCD0) ===================
        for (int t = 0; t < SEQ; ++t) {
            f32x16 acc;
#pragma unroll
            for (int j = 0; j < 16; ++j) acc[j] = 0.0f;

            if (t > 0) {
                const f16* hb = a.ring + (size_t)((t - 1) & (NRING - 1)) * HSTEP;
                uint4 Bh[32];
#pragma unroll
                for (int f = 0; f < 32; ++f)
                    Bh[f] = *(const uint4*)(hb + ((f * 2 + nh) * 64 + b) * 8);
#pragma unroll
                for (int g = 0; g < 4; ++g) {
                    f16x8 Af[8];
#pragma unroll
                    for (int j = 0; j < 8; ++j)
                        Af[j] = *(const f16x8*)
                            &wlds[(size_t)((ri * 32 + g * 8 + j) * 64 + lane) * 8];
#pragma unroll
                    for (int j = 0; j < 8; ++j)
                        acc = __builtin_amdgcn_mfma_f32_32x32x16_f16(
                            Af[j], __builtin_bit_cast(f16x8, Bh[g * 8 + j]), acc, 0, 0, 0);
                }
            }

            // cell (lane = batch b, units slot*16+ri*8+nh*4 ..+4)
            f16x4 x0 = __builtin_bit_cast(f16x4, xq0);
            f16x4 x1 = __builtin_bit_cast(f16x4, xq1);
            f16x4 x2 = __builtin_bit_cast(f16x4, xq2);
            f16x4 x3 = __builtin_bit_cast(f16x4, xq3);
            f16 hh[4];
#pragma unroll
            for (int uu = 0; uu < 4; ++uu) {
                float gi = acc[uu]      + bf0[uu] + (float)x0[uu];
                float gf = acc[4 + uu]  + bf1[uu] + (float)x1[uu];
                float gg = acc[8 + uu]  + bf2[uu] + (float)x2[uu];
                float go = acc[12 + uu] + bf3[uu] + (float)x3[uu];
                float c_ = (t > 0) ? cst[uu] : 0.0f;
                float cn = sigmoidf_(gf) * c_ + sigmoidf_(gi) * tanhf_(gg);
                float hv = sigmoidf_(go) * tanhf_(cn);
                cst[uu] = cn;
                hh[uu] = (f16)hv;
            }
            union { f16x4 h; u64 d; } hp;
            hp.h = (f16x4){hh[0], hh[1], hh[2], hh[3]};
            // local ring (plain store -> XCD0 L2), then MALL publish
            *(u64*)(a.ring + (size_t)(t & (NRING - 1)) * HSTEP + hidx) = hp.d;
            (void)__hip_atomic_exchange((u64*)(a.h1pub + (size_t)t * HSTEP + hidx),
                                        hp.d, __ATOMIC_RELAXED, __HIP_MEMORY_SCOPE_AGENT);

            asm volatile("s_waitcnt vmcnt(0)" ::: "memory");
            if (lane == 0) l2_swap32(a.l0f + slot * 16 + w, (u32)(t + 1));

            // x prefetch for t+1 (in flight during spin)
            if (t + 1 < SEQ) {
                int sd = a.sidx[(t + 1) * 64 + b];
                if (sd >= 0) {
                    const f16* xp = a.W0P + (size_t)sd * 2048 + slot * 64 + ri * 8 + nh * 4;
                    xq0 = *(const uint2*)(xp);
                    xq1 = *(const uint2*)(xp + 16);
                    xq2 = *(const uint2*)(xp + 32);
                    xq3 = *(const uint2*)(xp + 48);
                } else {
                    xq0 = xq1 = xq2 = xq3 = (uint2){0, 0};
                }
            }

            if (w == 0) spin2(a.l0f, (u32)(t + 1), nullptr, 0u, lane);
            __syncthreads();   // all waves' pub exchanges drained (pre-barrier vmcnt)
            if (w == 0 && lane == 0)
                (void)__hip_atomic_exchange(a.pubf + slot * 16, (u32)(t + 1),
                                            __ATOMIC_RELAXED, __HIP_MEMORY_SCOPE_AGENT);
            asm volatile("" ::: "memory");
            __builtin_amdgcn_sched_barrier(0);
        }
    } else {
        // =================== L1 group (XCD1) ===================
        if (w == 0) spin2(a.l1f, 0u, a.pubf, 1u, lane);   // wait h1[0] published
        __syncthreads();
        asm volatile("" ::: "memory");
        __builtin_amdgcn_sched_barrier(0);

        for (int t = 0; t < SEQ; ++t) {
            f32x16 acc;
#pragma unroll
            for (int j = 0; j < 16; ++j) acc[j] = 0.0f;

            // issue LOCAL h2 loads first, MALL h1pub second (in-order vmcnt:
            // local results usable while pub still in flight)
            uint4 Bh2[32], Bh1[32];
            if (t > 0) {
                const f16* hb2 = a.h2 + (size_t)(t - 1) * HSTEP;
#pragma unroll
                for (int f = 0; f < 32; ++f)
                    Bh2[f] = *(const uint4*)(hb2 + ((f * 2 + nh) * 64 + b) * 8);
            }
            {
                const f16* hb1 = a.h1pub + (size_t)t * HSTEP;
#pragma unroll
                for (int f = 0; f < 32; ++f)
                    Bh1[f] = *(const uint4*)(hb1 + ((f * 2 + nh) * 64 + b) * 8);
            }
            if (t > 0) {   // hh term: A = Whh1 (m=1)
#pragma unroll
                for (int g = 0; g < 4; ++g) {
                    f16x8 Af[8];
#pragma unroll
                    for (int j = 0; j < 8; ++j)
                        Af[j] = *(const f16x8*)
                            &wlds[(size_t)(((2 + ri) * 32 + g * 8 + j) * 64 + lane) * 8];
#pragma unroll
                    for (int j = 0; j < 8; ++j)
                        acc = __builtin_amdgcn_mfma_f32_32x32x16_f16(
                            Af[j], __builtin_bit_cast(f16x8, Bh2[g * 8 + j]), acc, 0, 0, 0);
                }
            }
            {   // ih term: A = Wih1 (m=0), B = h1pub[t]
#pragma unroll
                for (int g = 0; g < 4; ++g) {
                    f16x8 Af[8];
#pragma unroll
                    for (int j = 0; j < 8; ++j)
                        Af[j] = *(const f16x8*)
                            &wlds[(size_t)((ri * 32 + g * 8 + j) * 64 + lane) * 8];
#pragma unroll
                    for (int j = 0; j < 8; ++j)
                        acc = __builtin_amdgcn_mfma_f32_32x32x16_f16(
                            Af[j], __builtin_bit_cast(f16x8, Bh1[g * 8 + j]), acc, 0, 0, 0);
                }
            }

            f16 hh[4];
#pragma unroll
            for (int uu = 0; uu < 4; ++uu) {
                float gi = acc[uu]      + bf0[uu];
                float gf = acc[4 + uu]  + bf1[uu];
                float gg = acc[8 + uu]  + bf2[uu];
                float go = acc[12 + uu] + bf3[uu];
                float c_ = (t > 0) ? cst[uu] : 0.0f;
                float cn = sigmoidf_(gf) * c_ + sigmoidf_(gi) * tanhf_(gg);
                float hv = sigmoidf_(go) * tanhf_(cn);
                cst[uu] = cn;
                hh[uu] = (f16)hv;
            }
            union { f16x4 h; u64 d; } hp;
            hp.h = (f16x4){hh[0], hh[1], hh[2], hh[3]};
            // local store only; proj sees it via end-of-kernel flush
            *(u64*)(a.h2 + (size_t)t * HSTEP + hidx) = hp.d;

            if (t + 1 < SEQ) {
                asm volatile("s_waitcnt vmcnt(0)" ::: "memory");
                if (lane == 0) l2_swap32(a.l1f + slot * 16 + w, (u32)(t + 1));
                if (w == 0) spin2(a.l1f, (u32)(t + 1), a.pubf, (u32)(t + 2), lane);
                __syncthreads();
                asm volatile("" ::: "memory");
                __builtin_amdgcn_sched_barrier(0);
            }
        }
    }
}

// ---- projection (MFMA): out[b][t][n] = sigmoid(h2[t][b][:] . fcW[n] + fcb[n]) ----
__global__ __launch_bounds__(256) void proj_mfma(
    const f16* __restrict__ h2, const f16* __restrict__ fcwh,
    const float* __restrict__ fcb, float* __restrict__ out)
{
    const int tg = blockIdx.x >> 4;
    const int nt = blockIdx.x & 15;
    const int tid = threadIdx.x;
    const int l = tid & 63;
    const int w = tid >> 6;
    const int col = l & 15;
    const int kb = l >> 4;

    f32x4 acc[4][4];
#pragma unroll
    for (int j = 0; j < 4; ++j)
#pragma unroll
        for (int v = 0; v < 4; ++v) acc[j][v] = (f32x4){0, 0, 0, 0};

    float fb[4];
#pragma unroll
    for (int v = 0; v < 4; ++v) fb[v] = fcb[nt * 64 + v * 16 + col];

#pragma unroll 2
    for (int f = 0; f < 16; ++f) {
        f16x8 Bf[4];
#pragma unroll
        for (int v = 0; v < 4; ++v) {
            int nn = nt * 64 + v * 16 + col;
            Bf[v] = *(const f16x8*)(fcwh + (size_t)nn * HID + f * 32 + kb * 8);
        }
#pragma unroll
        for (int j = 0; j < 4; ++j) {
            const f16* hp = h2 + (size_t)(tg * 4 + j) * HSTEP
                          + ((f * 4 + kb) * 64 + (w * 16 + col)) * 8;
            uint4 au = *(const uint4*)hp;
#pragma unroll
            for (int v = 0; v < 4; ++v)
                acc[j][v] = __builtin_amdgcn_mfma_f32_16x16x32_f16(
                    __builtin_bit_cast(f16x8, au), Bf[v], acc[j][v], 0, 0, 0);
        }
    }
#pragma unroll
    for (int j = 0; j < 4; ++j) {
        int t = tg * 4 + j;
#pragma unroll
        for (int v = 0; v < 4; ++v) {
            int nn = nt * 64 + v * 16 + col;
#pragma unroll
            for (int r = 0; r < 4; ++r) {
                int b = w * 16 + kb * 4 + r;
                out[((size_t)b * SEQ + t) * NSK + nn] = sigmoidf_(acc[j][v][r] + fb[v]);
            }
        }
    }
}

extern "C" void kernel_launch(void* const* d_in, const int* in_sizes, int n_in,
                              void* d_out, int out_size, void* d_ws, size_t ws_size,
                              hipStream_t stream) {
    (void)in_sizes; (void)n_in; (void)out_size; (void)ws_size;

    const int*   skills   = (const int*)d_in[0];
    const int*   corrects = (const int*)d_in[1];
    const float* Wih0 = (const float*)d_in[2];
    const float* Whh0 = (const float*)d_in[3];
    const float* bih0 = (const float*)d_in[4];
    const float* bhh0 = (const float*)d_in[5];
    const float* Wih1 = (const float*)d_in[6];
    const float* Whh1 = (const float*)d_in[7];
    const float* bih1 = (const float*)d_in[8];
    const float* bhh1 = (const float*)d_in[9];
    const float* fcW  = (const float*)d_in[10];
    const float* fcb  = (const float*)d_in[11];

    char* ws = (char*)d_ws;
    f16*  h1pub = (f16*)(ws + H1PUB_OFF);
    f16*  h2    = (f16*)(ws + H2_OFF);
    f16*  ring  = (f16*)(ws + RING_OFF);
    f16*  fcwh  = (f16*)(ws + FCW_OFF);
    float* bfold = (float*)(ws + BF_OFF);
    int*  sidx  = (int*)(ws + SIDX_OFF);
    u32*  l0f   = (u32*)(ws + L0F_OFF);
    u32*  l1f   = (u32*)(ws + L1F_OFF);
    u32*  pubf  = (u32*)(ws + PUBF_OFF);
    u32*  cnt   = (u32*)(ws + CNT_OFF);
    f16*  w0p   = (f16*)(ws + W0P_OFF);

    prep_kernel<<<2048, 256, 0, stream>>>(skills, corrects, fcW,
                                          bih0, bhh0, bih1, bhh1,
                                          fcwh, bfold, sidx, l0f);
    w0p_kernel<<<1024, 256, 0, stream>>>(Wih0, w0p);

    PArgs pa;
    pa.sidx = sidx; pa.W0P = w0p;
    pa.Whh0 = Whh0; pa.Wih1 = Wih1; pa.Whh1 = Whh1;
    pa.bfold = bfold;
    pa.h1pub = h1pub; pa.h2 = h2; pa.ring = ring;
    pa.l0f = l0f; pa.l1f = l1f; pa.pubf = pubf; pa.cnt = cnt;

    lstm_mfma<<<256, 256, 0, stream>>>(pa);

    proj_mfma<<<2048, 256, 0, stream>>>(h2, fcwh, fcb, (float*)d_out);
}